// Round 9
// baseline (38.540 us; speedup 1.0000x reference)
//
#include <hip/hip_runtime.h>
#include <math.h>

#define CRF_B 2048
#define CRF_S 4096
#define LN2F  0.6931471805599453f

// Volatile asm loads: ordered among themselves, outputs pinned until use.
// Compiler cannot sink these to the use site -> all stay in flight together.
#define GLOADX4F(dst, base, OFF) \
    asm volatile("global_load_dwordx4 %0, %1, off offset:" #OFF \
                 : "=v"(dst) : "v"(base) : "memory")
#define GLOADX4I(dst, base, OFF) \
    asm volatile("global_load_dwordx4 %0, %1, off offset:" #OFF \
                 : "=v"(dst) : "v"(base) : "memory")
#define GLOADI(dst, base) \
    asm volatile("global_load_dword %0, %1, off" \
                 : "=v"(dst) : "v"(base) : "memory")

// Shared-exponent merge: A ∘= B where M = q[9] * 2^C (q renormalized so
// max q ~ [1,2)). R = A.q · B.q raw (27 FMA), single pow2 renorm, C adds.
#define CRF_MERGE(aq0,aq1,aq2,aq3,aq4,aq5,aq6,aq7,aq8,aC,asc,acn, \
                  bq0,bq1,bq2,bq3,bq4,bq5,bq6,bq7,bq8,bC,bsc,bcn) { \
    float r0_=aq0*bq0+aq1*bq3+aq2*bq6;                              \
    float r1_=aq0*bq1+aq1*bq4+aq2*bq7;                              \
    float r2_=aq0*bq2+aq1*bq5+aq2*bq8;                              \
    float r3_=aq3*bq0+aq4*bq3+aq5*bq6;                              \
    float r4_=aq3*bq1+aq4*bq4+aq5*bq7;                              \
    float r5_=aq3*bq2+aq4*bq5+aq5*bq8;                              \
    float r6_=aq6*bq0+aq7*bq3+aq8*bq6;                              \
    float r7_=aq6*bq1+aq7*bq4+aq8*bq7;                              \
    float r8_=aq6*bq2+aq7*bq5+aq8*bq8;                              \
    float mx_ = fmaxf(fmaxf(fmaxf(fmaxf(r0_,r1_),r2_),              \
                            fmaxf(fmaxf(r3_,r4_),r5_)),             \
                      fmaxf(fmaxf(r6_,r7_),r8_));                   \
    int ex_ = ((__float_as_int(mx_)>>23)&255)-127;                  \
    float sc_ = __int_as_float((127-ex_)<<23);                      \
    aq0=r0_*sc_; aq1=r1_*sc_; aq2=r2_*sc_;                          \
    aq3=r3_*sc_; aq4=r4_*sc_; aq5=r5_*sc_;                          \
    aq6=r6_*sc_; aq7=r7_*sc_; aq8=r8_*sc_;                          \
    aC = aC + bC + ex_;                                             \
    asc += bsc; acn += bcn; }

// One recursion step: q (3x3, rows) <- (q · Etr) * diag(exp(e)); emission
// score select. tconst is the compile-time step index within the chunk.
#define CRF_STEP(tconst, E0, E1, E2) {                               \
    int tv_ = (int)((ttag >> (2*(tconst))) & 3u);                    \
    int mv_ = (int)((tmsk >> (tconst)) & 1u);                        \
    if (mv_ && !(((tconst) == 0) && (tid == 0))) {                   \
        float X0_ = __expf(E0), X1_ = __expf(E1), X2_ = __expf(E2);  \
        float n0_, n1_, n2_;                                         \
        n0_ = q0*Etr0 + q1*Etr3 + q2*Etr6;                           \
        n1_ = q0*Etr1 + q1*Etr4 + q2*Etr7;                           \
        n2_ = q0*Etr2 + q1*Etr5 + q2*Etr8;                           \
        q0 = n0_*X0_; q1 = n1_*X1_; q2 = n2_*X2_;                    \
        n0_ = q3*Etr0 + q4*Etr3 + q5*Etr6;                           \
        n1_ = q3*Etr1 + q4*Etr4 + q5*Etr7;                           \
        n2_ = q3*Etr2 + q4*Etr5 + q5*Etr8;                           \
        q3 = n0_*X0_; q4 = n1_*X1_; q5 = n2_*X2_;                    \
        n0_ = q6*Etr0 + q7*Etr3 + q8*Etr6;                           \
        n1_ = q6*Etr1 + q7*Etr4 + q8*Etr7;                           \
        n2_ = q6*Etr2 + q7*Etr5 + q8*Etr8;                           \
        q6 = n0_*X0_; q7 = n1_*X1_; q8 = n2_*X2_;                    \
        sem += (tv_ == 0) ? (E0) : ((tv_ == 1) ? (E1) : (E2));       \
    } }

#define CRF_RENORM() {                                               \
    float mx_ = fmaxf(fmaxf(fmaxf(fmaxf(q0,q1),q2),                  \
                            fmaxf(fmaxf(q3,q4),q5)),                 \
                      fmaxf(fmaxf(q6,q7),q8));                       \
    int ex_ = ((__float_as_int(mx_) >> 23) & 255) - 127;             \
    float sc_ = __int_as_float((127 - ex_) << 23);                   \
    q0 *= sc_; q1 *= sc_; q2 *= sc_;                                 \
    q3 *= sc_; q4 *= sc_; q5 *= sc_;                                 \
    q6 *= sc_; q7 *= sc_; q8 *= sc_;                                 \
    C += ex_; }

// ---------------------------------------------------------------------------
// One block = one batch row. 256 threads (4 waves); lane owns a 16-step
// chunk. ALL chunk loads issued via volatile asm (cannot be sunk), Etr
// exp(LDS) work overlaps the in-flight loads, then ONE s_waitcnt vmcnt(0)
// -> single latency exposure per wave. Pure-register 16-step recursion in
// shared-exponent scaled-linear form, 6-level shfl_down log-semiring merge,
// 1 barrier, tid0 folds 3 wave-partials + epilogue.
// ---------------------------------------------------------------------------
__global__ __launch_bounds__(256, 4) void crf_row_kernel(
    const float* __restrict__ em,     // B*S*3
    const float* __restrict__ trans,  // 9
    const float* __restrict__ startt, // 3
    const float* __restrict__ endt,   // 3
    const int*   __restrict__ tags,   // B*S
    const int*   __restrict__ mask,   // B*S
    float* __restrict__ perb)         // B
{
    __shared__ float s_tr[9];
    __shared__ float s_rq[4][10];
    __shared__ int   s_rc[4][2];

    const int tid = threadIdx.x;      // chunk id within row (0..255)
    const int w = tid >> 6, l = tid & 63;
    const int b = blockIdx.x;
    const long cbase = (long)b * CRF_S + (long)tid * 16;

    if (tid < 9) s_tr[tid] = trans[tid];
    __syncthreads();                  // only lgkm traffic outstanding here

    // ---- issue ALL chunk loads via volatile asm (pinned in flight) ----
    const float* ebase = em + cbase * 3;                  // 192 B, 16B-aligned
    const int*   tbase = tags + cbase;
    const int*   mbase = mask + cbase;
    const int*   pbase = tags + cbase - ((tid > 0) ? 1 : 0);

    float4 ea0, ea1, ea2, ea3, ea4, ea5, ea6, ea7, ea8, ea9, ea10, ea11;
    int4 ta, tb, tc, td, ma, mb, mc, md;
    int pv;
    GLOADX4I(ta, tbase, 0);   GLOADX4I(tb, tbase, 16);
    GLOADX4I(tc, tbase, 32);  GLOADX4I(td, tbase, 48);
    GLOADX4I(ma, mbase, 0);   GLOADX4I(mb, mbase, 16);
    GLOADX4I(mc, mbase, 32);  GLOADX4I(md, mbase, 48);
    GLOADI(pv, pbase);
    GLOADX4F(ea0, ebase, 0);   GLOADX4F(ea1, ebase, 16);
    GLOADX4F(ea2, ebase, 32);  GLOADX4F(ea3, ebase, 48);
    GLOADX4F(ea4, ebase, 64);  GLOADX4F(ea5, ebase, 80);
    GLOADX4F(ea6, ebase, 96);  GLOADX4F(ea7, ebase, 112);
    GLOADX4F(ea8, ebase, 128); GLOADX4F(ea9, ebase, 144);
    GLOADX4F(ea10, ebase, 160); GLOADX4F(ea11, ebase, 176);

    // ---- overlap load latency with Etr = exp(trans) from LDS ----
    float Etr0 = __expf(s_tr[0]), Etr1 = __expf(s_tr[1]), Etr2 = __expf(s_tr[2]);
    float Etr3 = __expf(s_tr[3]), Etr4 = __expf(s_tr[4]), Etr5 = __expf(s_tr[5]);
    float Etr6 = __expf(s_tr[6]), Etr7 = __expf(s_tr[7]), Etr8 = __expf(s_tr[8]);

    asm volatile("s_waitcnt vmcnt(0)" ::: "memory");
    __builtin_amdgcn_sched_barrier(0);   // consumers must not hoist above wait

    // ---- pack tags (2b) and mask (1b) into scalars (frees the int4 regs) ----
    unsigned ttag =  (unsigned)(ta.x & 3)        | ((unsigned)(ta.y & 3) << 2)
                  | ((unsigned)(ta.z & 3) << 4)  | ((unsigned)(ta.w & 3) << 6)
                  | ((unsigned)(tb.x & 3) << 8)  | ((unsigned)(tb.y & 3) << 10)
                  | ((unsigned)(tb.z & 3) << 12) | ((unsigned)(tb.w & 3) << 14)
                  | ((unsigned)(tc.x & 3) << 16) | ((unsigned)(tc.y & 3) << 18)
                  | ((unsigned)(tc.z & 3) << 20) | ((unsigned)(tc.w & 3) << 22)
                  | ((unsigned)(td.x & 3) << 24) | ((unsigned)(td.y & 3) << 26)
                  | ((unsigned)(td.z & 3) << 28) | ((unsigned)(td.w & 3) << 30);
    unsigned tmsk =  (unsigned)(ma.x != 0)        | ((unsigned)(ma.y != 0) << 1)
                  | ((unsigned)(ma.z != 0) << 2)  | ((unsigned)(ma.w != 0) << 3)
                  | ((unsigned)(mb.x != 0) << 4)  | ((unsigned)(mb.y != 0) << 5)
                  | ((unsigned)(mb.z != 0) << 6)  | ((unsigned)(mb.w != 0) << 7)
                  | ((unsigned)(mc.x != 0) << 8)  | ((unsigned)(mc.y != 0) << 9)
                  | ((unsigned)(mc.z != 0) << 10) | ((unsigned)(mc.w != 0) << 11)
                  | ((unsigned)(md.x != 0) << 12) | ((unsigned)(md.y != 0) << 13)
                  | ((unsigned)(md.z != 0) << 14) | ((unsigned)(md.w != 0) << 15);
    int p = (tid > 0) ? (pv & 3) : 0;

    // ---- transition-score pre-pass: 16 independent LDS lookups ----
    float str_sum = 0.f;
    {
        int pr = p;
        #pragma unroll
        for (int t = 0; t < 16; ++t) {
            int tv = (int)((ttag >> (2 * t)) & 3u);
            if (((tmsk >> t) & 1u) && !((t == 0) && (tid == 0)))
                str_sum += s_tr[pr * 3 + tv];
            pr = tv;
        }
    }
    int cnt = __popc(tmsk & ((tid == 0) ? 0xFFFEu : 0xFFFFu));

    float q0=1.f,q1=0.f,q2=0.f, q3=0.f,q4=1.f,q5=0.f, q6=0.f,q7=0.f,q8=1.f;
    int C = 0;
    float sem = 0.f;   // emission part of gold score

    float et0 = ea0.x, et1 = ea0.y, et2 = ea0.z;   // em[b,chunk,0,:] (epilogue)

    CRF_STEP( 0, ea0.x, ea0.y, ea0.z);
    CRF_STEP( 1, ea0.w, ea1.x, ea1.y);
    CRF_STEP( 2, ea1.z, ea1.w, ea2.x);
    CRF_STEP( 3, ea2.y, ea2.z, ea2.w);
    CRF_RENORM();
    CRF_STEP( 4, ea3.x, ea3.y, ea3.z);
    CRF_STEP( 5, ea3.w, ea4.x, ea4.y);
    CRF_STEP( 6, ea4.z, ea4.w, ea5.x);
    CRF_STEP( 7, ea5.y, ea5.z, ea5.w);
    CRF_RENORM();
    CRF_STEP( 8, ea6.x, ea6.y, ea6.z);
    CRF_STEP( 9, ea6.w, ea7.x, ea7.y);
    CRF_STEP(10, ea7.z, ea7.w, ea8.x);
    CRF_STEP(11, ea8.y, ea8.z, ea8.w);
    CRF_RENORM();
    CRF_STEP(12, ea9.x, ea9.y, ea9.z);
    CRF_STEP(13, ea9.w, ea10.x, ea10.y);
    CRF_STEP(14, ea10.z, ea10.w, ea11.x);
    CRF_STEP(15, ea11.y, ea11.z, ea11.w);
    CRF_RENORM();

    float score = str_sum + sem;

    // ---- per-wave shfl_down log-semiring reduction ----
    #pragma unroll
    for (int st = 1; st < 64; st <<= 1) {
        float nq0 = __shfl_down(q0, st), nq1 = __shfl_down(q1, st),
              nq2 = __shfl_down(q2, st), nq3 = __shfl_down(q3, st),
              nq4 = __shfl_down(q4, st), nq5 = __shfl_down(q5, st),
              nq6 = __shfl_down(q6, st), nq7 = __shfl_down(q7, st),
              nq8 = __shfl_down(q8, st);
        int   nC  = __shfl_down(C, st);
        float nsc = __shfl_down(score, st);
        int   ncn = __shfl_down(cnt, st);
        CRF_MERGE(q0,q1,q2,q3,q4,q5,q6,q7,q8,C,score,cnt,
                  nq0,nq1,nq2,nq3,nq4,nq5,nq6,nq7,nq8,nC,nsc,ncn);
    }

    if (l == 0) {
        s_rq[w][0]=q0; s_rq[w][1]=q1; s_rq[w][2]=q2;
        s_rq[w][3]=q3; s_rq[w][4]=q4; s_rq[w][5]=q5;
        s_rq[w][6]=q6; s_rq[w][7]=q7; s_rq[w][8]=q8;
        s_rq[w][9]=score;
        s_rc[w][0]=C;  s_rc[w][1]=cnt;
    }
    __syncthreads();

    if (tid == 0) {
        float a0=q0, a1=q1, a2=q2, a3=q3, a4=q4, a5=q5, a6=q6, a7=q7, a8=q8;
        float asc = score;
        int AC = C, acn = cnt;
        #pragma unroll
        for (int w2 = 1; w2 < 4; ++w2) {
            float m0=s_rq[w2][0], m1=s_rq[w2][1], m2=s_rq[w2][2],
                  m3=s_rq[w2][3], m4=s_rq[w2][4], m5=s_rq[w2][5],
                  m6=s_rq[w2][6], m7=s_rq[w2][7], m8=s_rq[w2][8];
            float msc = s_rq[w2][9];
            int mC = s_rc[w2][0], mcn = s_rc[w2][1];
            CRF_MERGE(a0,a1,a2,a3,a4,a5,a6,a7,a8,AC,asc,acn,
                      m0,m1,m2,m3,m4,m5,m6,m7,m8,mC,msc,mcn);
        }
        // ---- epilogue (tid 0 holds et0..2 = em[b,0,:], tag0, mask0) ----
        int tg0 = (int)(ttag & 3u), mk0 = (int)(tmsk & 1u);
        float la0 = startt[0] + et0;
        float la1 = startt[1] + et1;
        float la2 = startt[2] + et2;
        float am = fmaxf(fmaxf(la0, la1), la2);
        float w0  = __expf(la0 - am);
        float w1  = __expf(la1 - am);
        float w2v = __expf(la2 - am);
        float v0 = w0*a0 + w1*a3 + w2v*a6;
        float v1 = w0*a1 + w1*a4 + w2v*a7;
        float v2 = w0*a2 + w1*a5 + w2v*a8;
        float sum = v0 * __expf(endt[0]) + v1 * __expf(endt[1])
                  + v2 * __expf(endt[2]);
        float lp = am + (float)AC * LN2F + __logf(sum);

        float sc = asc + startt[tg0]
                 + ((tg0 == 0) ? et0 : (tg0 == 1) ? et1 : et2);
        int cn = acn + mk0;
        int lastidx = (cn > 0) ? (cn - 1) : 0;
        sc += endt[tags[(long)b * CRF_S + lastidx]];

        perb[b] = lp - sc;
    }
}

// ---------------------------------------------------------------------------
// Deterministic mean over B values.
// ---------------------------------------------------------------------------
__global__ __launch_bounds__(256) void crf_reduce_kernel(
    const float* __restrict__ perb, float* __restrict__ out)
{
    __shared__ float sdata[256];
    const int tid = threadIdx.x;
    float s = 0.f;
    for (int i = tid; i < CRF_B; i += 256) s += perb[i];
    sdata[tid] = s;
    __syncthreads();
    for (int off = 128; off > 0; off >>= 1) {
        if (tid < off) sdata[tid] += sdata[tid + off];
        __syncthreads();
    }
    if (tid == 0) out[0] = sdata[0] * (1.0f / (float)CRF_B);
}

extern "C" void kernel_launch(void* const* d_in, const int* in_sizes, int n_in,
                              void* d_out, int out_size, void* d_ws, size_t ws_size,
                              hipStream_t stream)
{
    const float* em     = (const float*)d_in[0];
    const float* trans  = (const float*)d_in[1];
    const float* startt = (const float*)d_in[2];
    const float* endt   = (const float*)d_in[3];
    const int*   tags   = (const int*)d_in[4];
    const int*   mask   = (const int*)d_in[5];
    float* out = (float*)d_out;

    float* perb = (float*)d_ws;   // B floats

    crf_row_kernel<<<CRF_B, 256, 0, stream>>>(
        em, trans, startt, endt, tags, mask, perb);
    crf_reduce_kernel<<<1, 256, 0, stream>>>(perb, out);
}